// Round 6
// baseline (393.633 us; speedup 1.0000x reference)
//
#include <hip/hip_runtime.h>

#define T_ 2048
#define C_ 64
#define LSTRIDE 148       // padded LDS stride (592 B = 37*16B): chain reads 2-way max
#define NQ_ 76            // matrices per block: p = t0 .. t0+75

// ------------------------------------------------------------------
// Quad-lane DPP broadcast: all 4 lanes of a quad get lane Q's value.
// ------------------------------------------------------------------
template <int Q>
__device__ __forceinline__ float qb(float v) {
  return __int_as_float(
      __builtin_amdgcn_mov_dpp(__float_as_int(v), Q * 0x55, 0xf, 0xf, true));
}

// C(3x12, own rows) = A(3x12) * B(12x12 quad-distributed) ; ACC: c += if true
template <bool ACC>
__device__ __forceinline__ void qmm_t(const float a[3][12], const float b[3][12],
                                      float c[3][12]) {
  if (!ACC) {
#pragma unroll
    for (int i = 0; i < 3; ++i)
#pragma unroll
      for (int j = 0; j < 12; ++j) c[i][j] = 0.f;
  }
#define QMM_K(OWNER, E)                                                  \
  {                                                                      \
    float bk[12];                                                        \
    _Pragma("unroll")                                                    \
    for (int j = 0; j < 12; ++j) bk[j] = qb<OWNER>(b[E][j]);             \
    _Pragma("unroll")                                                    \
    for (int i = 0; i < 3; ++i) {                                        \
      const float av = a[i][3 * OWNER + E];                              \
      _Pragma("unroll")                                                  \
      for (int j = 0; j < 12; ++j) c[i][j] = fmaf(av, bk[j], c[i][j]);   \
    }                                                                    \
  }
  QMM_K(0, 0) QMM_K(0, 1) QMM_K(0, 2)
  QMM_K(1, 0) QMM_K(1, 1) QMM_K(1, 2)
  QMM_K(2, 0) QMM_K(2, 1) QMM_K(2, 2)
  QMM_K(3, 0) QMM_K(3, 1) QMM_K(3, 2)
#undef QMM_K
}
__device__ __forceinline__ void qmm(const float a[3][12], const float b[3][12],
                                    float c[3][12]) { qmm_t<false>(a, b, c); }
__device__ __forceinline__ void qmma(const float a[3][12], const float b[3][12],
                                     float c[3][12]) { qmm_t<true>(a, b, c); }

// C(3x12, own rows) = A(3x12, own rows) * B(12x12 in LDS, rows contiguous)
__device__ __forceinline__ void matmul_rows(const float a[3][12],
                                            const float* lb, float c[3][12]) {
#pragma unroll
  for (int i = 0; i < 3; ++i)
#pragma unroll
    for (int j = 0; j < 12; ++j) c[i][j] = 0.f;
#pragma unroll
  for (int k = 0; k < 12; ++k) {
    float4 b0 = *(const float4*)(lb + k * 12 + 0);
    float4 b1 = *(const float4*)(lb + k * 12 + 4);
    float4 b2 = *(const float4*)(lb + k * 12 + 8);
#pragma unroll
    for (int i = 0; i < 3; ++i) {
      const float a_ = a[i][k];
      c[i][0] += a_ * b0.x;  c[i][1] += a_ * b0.y;  c[i][2]  += a_ * b0.z;  c[i][3]  += a_ * b0.w;
      c[i][4] += a_ * b1.x;  c[i][5] += a_ * b1.y;  c[i][6]  += a_ * b1.z;  c[i][7]  += a_ * b1.w;
      c[i][8] += a_ * b2.x;  c[i][9] += a_ * b2.y;  c[i][10] += a_ * b2.z;  c[i][11] += a_ * b2.w;
    }
  }
}

// ------------------------------------------------------------------
// Fully fused. __launch_bounds__(320, 1): let the allocator use up to the
// 256-VGPR arch max — rounds 4/5 proved that any tighter cap (84, 128)
// spills the ~160-float live set and generates GBs of scratch traffic.
// ------------------------------------------------------------------
__global__ __launch_bounds__(320, 1) void fused_kernel(const float* __restrict__ x,
                                                       const float* __restrict__ A,
                                                       float* __restrict__ out) {
  __shared__ float smem[NQ_ * LSTRIDE];   // 44992 B; ask (9216 floats) unions with eb
  const int b = blockIdx.y;
  const int t0 = blockIdx.x * 64;
  const int tid = threadIdx.x;
  const int q = tid >> 2;     // quad 0..79
  const int eg = tid & 3;     // lane in quad: owns rows 3eg..3eg+2

  // ---- stage scaled skew-symmetrized A into LDS ----
  float (*ask)[144] = (float (*)[144])smem;
  const float sc = 1.0f / 32.0f;   // 2^-5 folded in
  for (int i = tid; i < 64 * 144; i += 320) {
    int c = i / 144, e = i - c * 144;
    int h = e / 12, w = e - h * 12;
    ask[c][e] = (A[c * 144 + e] - A[c * 144 + w * 12 + h]) * sc;
  }

  // ---- dx for my quad's matrix p = t0+q, lane owns c in [16eg,16eg+16) ----
  float dxv[16];
  {
    const int p = t0 + q;                       // q<80 -> p<=2063, clamps safe
    const int i1 = min(max(p - 7, 0), T_ - 1);
    const int i2 = min(max(p - 5, 0), T_ - 1);
    const float* xb = x + (size_t)b * T_ * C_;
    const float4* r1 = (const float4*)(xb + (size_t)i1 * C_ + 16 * eg);
    const float4* r2 = (const float4*)(xb + (size_t)i2 * C_ + 16 * eg);
#pragma unroll
    for (int m = 0; m < 4; ++m) {
      float4 v1 = r1[m], v2 = r2[m];
      dxv[4 * m + 0] = v2.x - v1.x;
      dxv[4 * m + 1] = v2.y - v1.y;
      dxv[4 * m + 2] = v2.z - v1.z;
      dxv[4 * m + 3] = v2.w - v1.w;
    }
  }
  __syncthreads();

  // ---- build my 3 rows of scaled M: a = sum_c dx[c] * ask[c][rows] ----
  float a[3][12];
  float* af = &a[0][0];
#pragma unroll
  for (int j = 0; j < 36; ++j) af[j] = 0.f;
  const int e0 = eg * 36;
#define BUILD_BLK(OWNER)                                                 \
  _Pragma("unroll")                                                      \
  for (int cc = 0; cc < 16; ++cc) {                                      \
    float d = qb<OWNER>(dxv[cc]);                                        \
    const float4* ar = (const float4*)&ask[OWNER * 16 + cc][e0];         \
    _Pragma("unroll")                                                    \
    for (int qq = 0; qq < 9; ++qq) {                                     \
      float4 v = ar[qq];                                                 \
      af[qq * 4 + 0] = fmaf(d, v.x, af[qq * 4 + 0]);                     \
      af[qq * 4 + 1] = fmaf(d, v.y, af[qq * 4 + 1]);                     \
      af[qq * 4 + 2] = fmaf(d, v.z, af[qq * 4 + 2]);                     \
      af[qq * 4 + 3] = fmaf(d, v.w, af[qq * 4 + 3]);                     \
    }                                                                    \
  }
  BUILD_BLK(0) BUILD_BLK(1) BUILD_BLK(2) BUILD_BLK(3)
#undef BUILD_BLK
  __syncthreads();   // last ask read done -> smem reusable as eb

  // ---- expm: Paterson-Stockmeyer degree-6 (3 mults) + 5 squarings ----
  float t2[3][12], t3[3][12], pp[3][12];
  qmm(a, a, t2);      // M2
  qmm(t2, a, t3);     // M3
#pragma unroll
  for (int i = 0; i < 3; ++i)
#pragma unroll
    for (int j = 0; j < 12; ++j)
      pp[i][j] = a[i][j] + t2[i][j] * 0.5f + t3[i][j] * (1.0f / 6.0f) +
                 ((j == 3 * eg + i) ? 1.0f : 0.0f);
  // a <- W = M/24 + M2/120 + M3/720  (t2 dead after this)
#pragma unroll
  for (int i = 0; i < 3; ++i)
#pragma unroll
    for (int j = 0; j < 12; ++j)
      a[i][j] = a[i][j] * (1.0f / 24.0f) + t2[i][j] * (1.0f / 120.0f) +
                t3[i][j] * (1.0f / 720.0f);
  qmma(t3, a, pp);    // pp += M3*W = M4/24 + M5/120 + M6/720
  // 5 squarings: result lands in t2
  qmm(pp, pp, t2);
  qmm(t2, t2, pp);
  qmm(pp, pp, t2);
  qmm(t2, t2, pp);
  qmm(pp, pp, t2);    // E in t2

  // ---- E -> LDS ----
  float (*eb)[LSTRIDE] = (float (*)[LSTRIDE])smem;
  if (q < NQ_) {
    float* lb = &eb[q][0];
#pragma unroll
    for (int i = 0; i < 3; ++i) {
      const int row = 3 * eg + i;
      *(float4*)(lb + row * 12 + 0) = make_float4(t2[i][0], t2[i][1], t2[i][2],  t2[i][3]);
      *(float4*)(lb + row * 12 + 4) = make_float4(t2[i][4], t2[i][5], t2[i][6],  t2[i][7]);
      *(float4*)(lb + row * 12 + 8) = make_float4(t2[i][8], t2[i][9], t2[i][10], t2[i][11]);
    }
  }
  __syncthreads();

  // ---- chain: quads 0..63 own window t = t0+q ----
  if (q < 64) {
    const int t = t0 + q;
    float z[3][12], c[3][12];
#pragma unroll
    for (int i = 0; i < 3; ++i) {
      const float* zp = &eb[q][(3 * eg + i) * 12];
      float4 v0 = *(const float4*)(zp + 0);
      float4 v1 = *(const float4*)(zp + 4);
      float4 v2 = *(const float4*)(zp + 8);
      z[i][0] = v0.x; z[i][1] = v0.y; z[i][2]  = v0.z; z[i][3]  = v0.w;
      z[i][4] = v1.x; z[i][5] = v1.y; z[i][6]  = v1.z; z[i][7]  = v1.w;
      z[i][8] = v2.x; z[i][9] = v2.y; z[i][10] = v2.z; z[i][11] = v2.w;
    }
    matmul_rows(z, &eb[q + 2][0], c);
    matmul_rows(c, &eb[q + 4][0], z);
    matmul_rows(z, &eb[q + 6][0], c);
    matmul_rows(c, &eb[q + 8][0], z);
    matmul_rows(z, &eb[q + 10][0], c);
    matmul_rows(c, &eb[q + 12][0], z);

    const size_t obase = ((size_t)b * T_ + t) * 208;
#pragma unroll
    for (int i = 0; i < 3; ++i) {
      const int row = 3 * eg + i;
      *(float4*)(out + obase + row * 12 + 0) = make_float4(z[i][0], z[i][1], z[i][2],  z[i][3]);
      *(float4*)(out + obase + row * 12 + 4) = make_float4(z[i][4], z[i][5], z[i][6],  z[i][7]);
      *(float4*)(out + obase + row * 12 + 8) = make_float4(z[i][8], z[i][9], z[i][10], z[i][11]);
    }
    const int xi = min(max(t - 7, 0), T_ - 1);
    const float* xr = x + ((size_t)b * T_ + xi) * C_ + 16 * eg;
#pragma unroll
    for (int m = 0; m < 4; ++m) {
      *(float4*)(out + obase + 144 + 16 * eg + m * 4) = *(const float4*)(xr + m * 4);
    }
  }
}

// ------------------------------------------------------------------
extern "C" void kernel_launch(void* const* d_in, const int* in_sizes, int n_in,
                              void* d_out, int out_size, void* d_ws, size_t ws_size,
                              hipStream_t stream) {
  (void)in_sizes; (void)n_in; (void)out_size; (void)d_ws; (void)ws_size;
  const float* x = (const float*)d_in[0];
  const float* A = (const float*)d_in[1];
  float* out = (float*)d_out;

  fused_kernel<<<dim3(T_ / 64, 32), 320, 0, stream>>>(x, A, out);
}

// Round 7
// 393.170 us; speedup vs baseline: 1.0012x; 1.0012x over previous
//
#include <hip/hip_runtime.h>

#define T_ 2048
#define C_ 64
#define LSTRIDE 148       // padded LDS stride (592 B = 37*16B): chain reads 2-way max
#define NQ_ 76            // matrices per block: p = t0 .. t0+75

// ------------------------------------------------------------------
// Quad-lane DPP broadcast: all 4 lanes of a quad get lane Q's value.
// ------------------------------------------------------------------
template <int Q>
__device__ __forceinline__ float qb(float v) {
  return __int_as_float(
      __builtin_amdgcn_mov_dpp(__float_as_int(v), Q * 0x55, 0xf, 0xf, true));
}

// C(3x12, own rows) = A(3x12) * B(12x12 quad-distributed) ; ACC: c += if true
template <bool ACC>
__device__ __forceinline__ void qmm_t(const float a[3][12], const float b[3][12],
                                      float c[3][12]) {
  if (!ACC) {
#pragma unroll
    for (int i = 0; i < 3; ++i)
#pragma unroll
      for (int j = 0; j < 12; ++j) c[i][j] = 0.f;
  }
#define QMM_K(OWNER, E)                                                  \
  {                                                                      \
    float bk[12];                                                        \
    _Pragma("unroll")                                                    \
    for (int j = 0; j < 12; ++j) bk[j] = qb<OWNER>(b[E][j]);             \
    _Pragma("unroll")                                                    \
    for (int i = 0; i < 3; ++i) {                                        \
      const float av = a[i][3 * OWNER + E];                              \
      _Pragma("unroll")                                                  \
      for (int j = 0; j < 12; ++j) c[i][j] = fmaf(av, bk[j], c[i][j]);   \
    }                                                                    \
  }
  QMM_K(0, 0) QMM_K(0, 1) QMM_K(0, 2)
  QMM_K(1, 0) QMM_K(1, 1) QMM_K(1, 2)
  QMM_K(2, 0) QMM_K(2, 1) QMM_K(2, 2)
  QMM_K(3, 0) QMM_K(3, 1) QMM_K(3, 2)
#undef QMM_K
}
__device__ __forceinline__ void qmm(const float a[3][12], const float b[3][12],
                                    float c[3][12]) { qmm_t<false>(a, b, c); }
__device__ __forceinline__ void qmma(const float a[3][12], const float b[3][12],
                                     float c[3][12]) { qmm_t<true>(a, b, c); }

// C(3x12, own rows) = A(3x12, own rows) * B(12x12 in LDS, rows contiguous)
__device__ __forceinline__ void matmul_rows(const float a[3][12],
                                            const float* lb, float c[3][12]) {
#pragma unroll
  for (int i = 0; i < 3; ++i)
#pragma unroll
    for (int j = 0; j < 12; ++j) c[i][j] = 0.f;
#pragma unroll
  for (int k = 0; k < 12; ++k) {
    float4 b0 = *(const float4*)(lb + k * 12 + 0);
    float4 b1 = *(const float4*)(lb + k * 12 + 4);
    float4 b2 = *(const float4*)(lb + k * 12 + 8);
#pragma unroll
    for (int i = 0; i < 3; ++i) {
      const float a_ = a[i][k];
      c[i][0] += a_ * b0.x;  c[i][1] += a_ * b0.y;  c[i][2]  += a_ * b0.z;  c[i][3]  += a_ * b0.w;
      c[i][4] += a_ * b1.x;  c[i][5] += a_ * b1.y;  c[i][6]  += a_ * b1.z;  c[i][7]  += a_ * b1.w;
      c[i][8] += a_ * b2.x;  c[i][9] += a_ * b2.y;  c[i][10] += a_ * b2.z;  c[i][11] += a_ * b2.w;
    }
  }
}

// ------------------------------------------------------------------
// Fully fused; expm restructured so at most THREE 36-float arrays are live
// at any point (rounds 4-6: four live arrays -> spill -> 1 GB scratch traffic).
// ------------------------------------------------------------------
__global__ __launch_bounds__(320) void fused_kernel(const float* __restrict__ x,
                                                    const float* __restrict__ A,
                                                    float* __restrict__ out) {
  __shared__ float smem[NQ_ * LSTRIDE];   // 44992 B; ask (9216 floats) unions with eb
  const int b = blockIdx.y;
  const int t0 = blockIdx.x * 64;
  const int tid = threadIdx.x;
  const int q = tid >> 2;     // quad 0..79
  const int eg = tid & 3;     // lane in quad: owns rows 3eg..3eg+2

  // ---- stage scaled skew-symmetrized A into LDS ----
  float (*ask)[144] = (float (*)[144])smem;
  const float sc = 1.0f / 32.0f;   // 2^-5 folded in
  for (int i = tid; i < 64 * 144; i += 320) {
    int c = i / 144, e = i - c * 144;
    int h = e / 12, w = e - h * 12;
    ask[c][e] = (A[c * 144 + e] - A[c * 144 + w * 12 + h]) * sc;
  }

  // ---- dx for my quad's matrix p = t0+q, lane owns c in [16eg,16eg+16) ----
  float dxv[16];
  {
    const int p = t0 + q;                       // q<80 -> p<=2063, clamps safe
    const int i1 = min(max(p - 7, 0), T_ - 1);
    const int i2 = min(max(p - 5, 0), T_ - 1);
    const float* xb = x + (size_t)b * T_ * C_;
    const float4* r1 = (const float4*)(xb + (size_t)i1 * C_ + 16 * eg);
    const float4* r2 = (const float4*)(xb + (size_t)i2 * C_ + 16 * eg);
#pragma unroll
    for (int m = 0; m < 4; ++m) {
      float4 v1 = r1[m], v2 = r2[m];
      dxv[4 * m + 0] = v2.x - v1.x;
      dxv[4 * m + 1] = v2.y - v1.y;
      dxv[4 * m + 2] = v2.z - v1.z;
      dxv[4 * m + 3] = v2.w - v1.w;
    }
  }
  __syncthreads();

  // ---- build my 3 rows of scaled M: a = sum_c dx[c] * ask[c][rows] ----
  float a[3][12];
  float* af = &a[0][0];
#pragma unroll
  for (int j = 0; j < 36; ++j) af[j] = 0.f;
  const int e0 = eg * 36;
#define BUILD_BLK(OWNER)                                                 \
  _Pragma("unroll")                                                      \
  for (int cc = 0; cc < 16; ++cc) {                                      \
    float d = qb<OWNER>(dxv[cc]);                                        \
    const float4* ar = (const float4*)&ask[OWNER * 16 + cc][e0];         \
    _Pragma("unroll")                                                    \
    for (int qq = 0; qq < 9; ++qq) {                                     \
      float4 v = ar[qq];                                                 \
      af[qq * 4 + 0] = fmaf(d, v.x, af[qq * 4 + 0]);                     \
      af[qq * 4 + 1] = fmaf(d, v.y, af[qq * 4 + 1]);                     \
      af[qq * 4 + 2] = fmaf(d, v.z, af[qq * 4 + 2]);                     \
      af[qq * 4 + 3] = fmaf(d, v.w, af[qq * 4 + 3]);                     \
    }                                                                    \
  }
  BUILD_BLK(0) BUILD_BLK(1) BUILD_BLK(2) BUILD_BLK(3)
#undef BUILD_BLK
  __syncthreads();   // last ask read done -> smem reusable as eb

  // ---- expm: PS-6 Taylor + 5 squarings, max 3 arrays live ----
  float t2[3][12], t3[3][12];
  qmm(a, a, t2);      // t2 = M2      (live: a, t2)
  qmm(t2, a, t3);     // t3 = M3      (live: a, t2, t3)

  // Fused elementwise overwrite:  t2 <- P_low = I + M + M2/2 + M3/6
  //                               a  <- W     = M/24 + M2/120 + M3/720
  // Each element of a/t2/t3 is read once before its slot is rewritten.
#pragma unroll
  for (int i = 0; i < 3; ++i)
#pragma unroll
    for (int j = 0; j < 12; ++j) {
      const float av = a[i][j], t2v = t2[i][j], t3v = t3[i][j];
      t2[i][j] = av + t2v * 0.5f + t3v * (1.0f / 6.0f) +
                 ((j == 3 * eg + i) ? 1.0f : 0.0f);
      a[i][j] = av * (1.0f / 24.0f) + t2v * (1.0f / 120.0f) +
                t3v * (1.0f / 720.0f);
    }
  qmma(t3, a, t2);    // t2 += M3*W   (live: a(W), t2, t3 — 3 arrays, last use of a,t3)

  // 5 squarings, ping-pong t2 <-> t3 (2 arrays live); E lands in t3
  qmm(t2, t2, t3);
  qmm(t3, t3, t2);
  qmm(t2, t2, t3);
  qmm(t3, t3, t2);
  qmm(t2, t2, t3);

  // ---- E -> LDS ----
  float (*eb)[LSTRIDE] = (float (*)[LSTRIDE])smem;
  if (q < NQ_) {
    float* lb = &eb[q][0];
#pragma unroll
    for (int i = 0; i < 3; ++i) {
      const int row = 3 * eg + i;
      *(float4*)(lb + row * 12 + 0) = make_float4(t3[i][0], t3[i][1], t3[i][2],  t3[i][3]);
      *(float4*)(lb + row * 12 + 4) = make_float4(t3[i][4], t3[i][5], t3[i][6],  t3[i][7]);
      *(float4*)(lb + row * 12 + 8) = make_float4(t3[i][8], t3[i][9], t3[i][10], t3[i][11]);
    }
  }
  __syncthreads();

  // ---- chain: quads 0..63 own window t = t0+q ----
  if (q < 64) {
    const int t = t0 + q;
    float z[3][12], c[3][12];
#pragma unroll
    for (int i = 0; i < 3; ++i) {
      const float* zp = &eb[q][(3 * eg + i) * 12];
      float4 v0 = *(const float4*)(zp + 0);
      float4 v1 = *(const float4*)(zp + 4);
      float4 v2 = *(const float4*)(zp + 8);
      z[i][0] = v0.x; z[i][1] = v0.y; z[i][2]  = v0.z; z[i][3]  = v0.w;
      z[i][4] = v1.x; z[i][5] = v1.y; z[i][6]  = v1.z; z[i][7]  = v1.w;
      z[i][8] = v2.x; z[i][9] = v2.y; z[i][10] = v2.z; z[i][11] = v2.w;
    }
    matmul_rows(z, &eb[q + 2][0], c);
    matmul_rows(c, &eb[q + 4][0], z);
    matmul_rows(z, &eb[q + 6][0], c);
    matmul_rows(c, &eb[q + 8][0], z);
    matmul_rows(z, &eb[q + 10][0], c);
    matmul_rows(c, &eb[q + 12][0], z);

    const size_t obase = ((size_t)b * T_ + t) * 208;
#pragma unroll
    for (int i = 0; i < 3; ++i) {
      const int row = 3 * eg + i;
      *(float4*)(out + obase + row * 12 + 0) = make_float4(z[i][0], z[i][1], z[i][2],  z[i][3]);
      *(float4*)(out + obase + row * 12 + 4) = make_float4(z[i][4], z[i][5], z[i][6],  z[i][7]);
      *(float4*)(out + obase + row * 12 + 8) = make_float4(z[i][8], z[i][9], z[i][10], z[i][11]);
    }
    const int xi = min(max(t - 7, 0), T_ - 1);
    const float* xr = x + ((size_t)b * T_ + xi) * C_ + 16 * eg;
#pragma unroll
    for (int m = 0; m < 4; ++m) {
      *(float4*)(out + obase + 144 + 16 * eg + m * 4) = *(const float4*)(xr + m * 4);
    }
  }
}

// ------------------------------------------------------------------
extern "C" void kernel_launch(void* const* d_in, const int* in_sizes, int n_in,
                              void* d_out, int out_size, void* d_ws, size_t ws_size,
                              hipStream_t stream) {
  (void)in_sizes; (void)n_in; (void)out_size; (void)d_ws; (void)ws_size;
  const float* x = (const float*)d_in[0];
  const float* A = (const float*)d_in[1];
  float* out = (float*)d_out;

  fused_kernel<<<dim3(T_ / 64, 32), 320, 0, stream>>>(x, A, out);
}

// Round 8
// 134.846 us; speedup vs baseline: 2.9191x; 2.9157x over previous
//
#include <hip/hip_runtime.h>

#define B_ 32
#define T_ 2048
#define C_ 64
#define NP_ 2060          // unique p positions per batch: t + 2k, t<2048, k<7
#define MSTRIDE 144       // floats per 12x12 matrix in global ws
#define LSTRIDE 148       // padded LDS stride for k3 staging

// ------------------------------------------------------------------
// Quad-lane DPP broadcast: all 4 lanes of a quad get lane Q's value.
// ------------------------------------------------------------------
template <int Q>
__device__ __forceinline__ float qb(float v) {
  return __int_as_float(
      __builtin_amdgcn_mov_dpp(__float_as_int(v), Q * 0x55, 0xf, 0xf, true));
}

// C(3x12, own rows) = A(3x12) * B(12x12 quad-distributed) ; ACC: c += if true
template <bool ACC>
__device__ __forceinline__ void qmm_t(const float a[3][12], const float b[3][12],
                                      float c[3][12]) {
  if (!ACC) {
#pragma unroll
    for (int i = 0; i < 3; ++i)
#pragma unroll
      for (int j = 0; j < 12; ++j) c[i][j] = 0.f;
  }
#define QMM_K(OWNER, E)                                                  \
  {                                                                      \
    float bk[12];                                                        \
    _Pragma("unroll")                                                    \
    for (int j = 0; j < 12; ++j) bk[j] = qb<OWNER>(b[E][j]);             \
    _Pragma("unroll")                                                    \
    for (int i = 0; i < 3; ++i) {                                        \
      const float av = a[i][3 * OWNER + E];                              \
      _Pragma("unroll")                                                  \
      for (int j = 0; j < 12; ++j) c[i][j] = fmaf(av, bk[j], c[i][j]);   \
    }                                                                    \
  }
  QMM_K(0, 0) QMM_K(0, 1) QMM_K(0, 2)
  QMM_K(1, 0) QMM_K(1, 1) QMM_K(1, 2)
  QMM_K(2, 0) QMM_K(2, 1) QMM_K(2, 2)
  QMM_K(3, 0) QMM_K(3, 1) QMM_K(3, 2)
#undef QMM_K
}
__device__ __forceinline__ void qmm(const float a[3][12], const float b[3][12],
                                    float c[3][12]) { qmm_t<false>(a, b, c); }
__device__ __forceinline__ void qmma(const float a[3][12], const float b[3][12],
                                     float c[3][12]) { qmm_t<true>(a, b, c); }

// ------------------------------------------------------------------
// K1: M[b][p] = sum_c dx[p][c] * Ask[c], with Ask pre-scaled by 2^-5
//     (expm scaling folded in). xp[j] = x[clamp(j-7,0,2047)].
// ------------------------------------------------------------------
__global__ __launch_bounds__(256) void k1_build(const float* __restrict__ x,
                                                const float* __restrict__ A,
                                                float* __restrict__ M) {
  __shared__ float ask[64][144];   // skew-symmetrized, pre-scaled A
  __shared__ float dx[64][65];     // +1 pad: conflict-free column reads
  const int b = blockIdx.y;
  const int p0 = blockIdx.x * 64;
  const int tid = threadIdx.x;

  const float sc = 1.0f / 32.0f;   // 2^-5
  for (int i = tid; i < 64 * 144; i += 256) {
    int c = i / 144, e = i - c * 144;
    int h = e / 12, w = e - h * 12;
    ask[c][e] = (A[c * 144 + e] - A[c * 144 + w * 12 + h]) * sc;
  }
  for (int i = tid; i < 64 * 64; i += 256) {
    int pl = i >> 6, c = i & 63;
    int p = p0 + pl;
    float v = 0.f;
    if (p < NP_) {
      int i1 = min(max(p - 7, 0), T_ - 1);
      int i2 = min(max(p - 5, 0), T_ - 1);
      const float* xb = x + (size_t)b * T_ * C_;
      v = xb[(size_t)i2 * C_ + c] - xb[(size_t)i1 * C_ + c];
    }
    dx[pl][c] = v;
  }
  __syncthreads();

  const int eg = tid & 3;          // 4 col-groups of 36
  const int nl = tid >> 2;         // 64 p's per block
  const int p = p0 + nl;
  const int e0 = eg * 36;
  float acc[36];
#pragma unroll
  for (int j = 0; j < 36; ++j) acc[j] = 0.f;

  for (int c = 0; c < 64; ++c) {
    float d = dx[nl][c];
    const float4* ar = (const float4*)&ask[c][e0];
#pragma unroll
    for (int q = 0; q < 9; ++q) {
      float4 v = ar[q];
      acc[q * 4 + 0] += d * v.x;
      acc[q * 4 + 1] += d * v.y;
      acc[q * 4 + 2] += d * v.z;
      acc[q * 4 + 3] += d * v.w;
    }
  }
  if (p < NP_) {
    float* mp = M + ((size_t)b * NP_ + p) * MSTRIDE + e0;
#pragma unroll
    for (int q = 0; q < 9; ++q) {
      *(float4*)(mp + q * 4) =
          make_float4(acc[q * 4 + 0], acc[q * 4 + 1], acc[q * 4 + 2], acc[q * 4 + 3]);
    }
  }
}

// ------------------------------------------------------------------
// K2: in-place E = expm(32*Min) for pre-scaled Min. PS-6 Taylor (3 mults)
// + 5 squarings = 8 qmm. One quad per matrix, 3 rows/lane, all registers,
// max THREE 36-float arrays live at any point.
// ------------------------------------------------------------------
__global__ __launch_bounds__(256) void k2_expm(float* __restrict__ M) {
  const int gq = (blockIdx.x * 256 + threadIdx.x) >> 2;  // global matrix id
  const int r = threadIdx.x & 3;
  float* gp = M + (size_t)gq * MSTRIDE + 36 * r;  // my 3 rows, contiguous

  float a[3][12], t2[3][12], t3[3][12];
#pragma unroll
  for (int i = 0; i < 3; ++i)
#pragma unroll
    for (int q4 = 0; q4 < 3; ++q4) {
      float4 v = *(const float4*)(gp + i * 12 + q4 * 4);
      a[i][q4 * 4 + 0] = v.x;
      a[i][q4 * 4 + 1] = v.y;
      a[i][q4 * 4 + 2] = v.z;
      a[i][q4 * 4 + 3] = v.w;
    }

  qmm(a, a, t2);      // t2 = M2
  qmm(t2, a, t3);     // t3 = M3

  // Fused elementwise overwrite: t2 <- I + M + M2/2 + M3/6 ; a <- W
#pragma unroll
  for (int i = 0; i < 3; ++i)
#pragma unroll
    for (int j = 0; j < 12; ++j) {
      const float av = a[i][j], t2v = t2[i][j], t3v = t3[i][j];
      t2[i][j] = av + t2v * 0.5f + t3v * (1.0f / 6.0f) +
                 ((j == 3 * r + i) ? 1.0f : 0.0f);
      a[i][j] = av * (1.0f / 24.0f) + t2v * (1.0f / 120.0f) +
                t3v * (1.0f / 720.0f);
    }
  qmma(t3, a, t2);    // t2 += M3*W = M4/24 + M5/120 + M6/720

  // 5 squarings, ping-pong; E lands in t3
  qmm(t2, t2, t3);
  qmm(t3, t3, t2);
  qmm(t2, t2, t3);
  qmm(t3, t3, t2);
  qmm(t2, t2, t3);

#pragma unroll
  for (int i = 0; i < 3; ++i)
#pragma unroll
    for (int q4 = 0; q4 < 3; ++q4)
      *(float4*)(gp + i * 12 + q4 * 4) =
          make_float4(t3[i][q4 * 4 + 0], t3[i][q4 * 4 + 1],
                      t3[i][q4 * 4 + 2], t3[i][q4 * 4 + 3]);
}

// ------------------------------------------------------------------
// K3: per window t: Z = E(t) * E(t+2) * ... * E(t+12); out = [Z(144), xp[t](64)]
// 64 windows/block; stage 76 E's in LDS; per chain step load B rows to regs
// (9 ds_read_b128) then DPP qmm.  (Round-1 structure: measured ~9us faster
// than the 36-broadcast-read LDS matmul variant.)
// ------------------------------------------------------------------
__global__ __launch_bounds__(256) void k3_chain(const float* __restrict__ E,
                                                const float* __restrict__ x,
                                                float* __restrict__ out) {
  __shared__ float eb[76][LSTRIDE];
  const int b = blockIdx.y;
  const int t0 = blockIdx.x * 64;
  const float* src = E + ((size_t)b * NP_ + t0) * MSTRIDE;
  for (int i = threadIdx.x; i < 76 * 36; i += 256) {
    int m = i / 36, q = i - m * 36;
    *(float4*)(&eb[m][q * 4]) = *(const float4*)(src + (size_t)m * MSTRIDE + q * 4);
  }
  __syncthreads();

  const int r = threadIdx.x & 3;
  const int tl = threadIdx.x >> 2;  // 0..63, window within block
  const int t = t0 + tl;

  float z[3][12], c[3][12];
#pragma unroll
  for (int i = 0; i < 3; ++i) {
    const float* zp = &eb[tl][(3 * r + i) * 12];
    float4 v0 = *(const float4*)(zp + 0);
    float4 v1 = *(const float4*)(zp + 4);
    float4 v2 = *(const float4*)(zp + 8);
    z[i][0] = v0.x; z[i][1] = v0.y; z[i][2]  = v0.z; z[i][3]  = v0.w;
    z[i][4] = v1.x; z[i][5] = v1.y; z[i][6]  = v1.z; z[i][7]  = v1.w;
    z[i][8] = v2.x; z[i][9] = v2.y; z[i][10] = v2.z; z[i][11] = v2.w;
  }

#define CHAIN_STEP(SRC, DST, J)                                          \
  {                                                                      \
    float bb[3][12];                                                     \
    _Pragma("unroll")                                                    \
    for (int i = 0; i < 3; ++i) {                                        \
      const float* ep = &eb[tl + 2 * (J)][(3 * r + i) * 12];             \
      float4 v0 = *(const float4*)(ep + 0);                              \
      float4 v1 = *(const float4*)(ep + 4);                              \
      float4 v2 = *(const float4*)(ep + 8);                              \
      bb[i][0] = v0.x; bb[i][1] = v0.y; bb[i][2]  = v0.z; bb[i][3]  = v0.w; \
      bb[i][4] = v1.x; bb[i][5] = v1.y; bb[i][6]  = v1.z; bb[i][7]  = v1.w; \
      bb[i][8] = v2.x; bb[i][9] = v2.y; bb[i][10] = v2.z; bb[i][11] = v2.w; \
    }                                                                    \
    qmm(SRC, bb, DST);                                                   \
  }
  CHAIN_STEP(z, c, 1)
  CHAIN_STEP(c, z, 2)
  CHAIN_STEP(z, c, 3)
  CHAIN_STEP(c, z, 4)
  CHAIN_STEP(z, c, 5)
  CHAIN_STEP(c, z, 6)
#undef CHAIN_STEP

  const size_t obase = ((size_t)b * T_ + t) * 208;
#pragma unroll
  for (int i = 0; i < 3; ++i) {
    const int row = 3 * r + i;
    *(float4*)(out + obase + row * 12 + 0) = make_float4(z[i][0], z[i][1], z[i][2],  z[i][3]);
    *(float4*)(out + obase + row * 12 + 4) = make_float4(z[i][4], z[i][5], z[i][6],  z[i][7]);
    *(float4*)(out + obase + row * 12 + 8) = make_float4(z[i][8], z[i][9], z[i][10], z[i][11]);
  }
  const int xi = min(max(t - 7, 0), T_ - 1);
  const float* xr = x + ((size_t)b * T_ + xi) * C_ + 16 * r;
#pragma unroll
  for (int q = 0; q < 4; ++q) {
    *(float4*)(out + obase + 144 + 16 * r + q * 4) = *(const float4*)(xr + q * 4);
  }
}

// ------------------------------------------------------------------
extern "C" void kernel_launch(void* const* d_in, const int* in_sizes, int n_in,
                              void* d_out, int out_size, void* d_ws, size_t ws_size,
                              hipStream_t stream) {
  (void)in_sizes; (void)n_in; (void)out_size;
  const float* x = (const float*)d_in[0];
  const float* A = (const float*)d_in[1];
  float* out = (float*)d_out;
  float* M = (float*)d_ws;

  const size_t need = (size_t)B_ * NP_ * MSTRIDE * sizeof(float);  // ~38 MB
  if (ws_size < need) return;

  k1_build<<<dim3(33, B_), 256, 0, stream>>>(x, A, M);
  k2_expm<<<dim3((B_ * NP_ * 4) / 256), 256, 0, stream>>>(M);  // 1030 blocks
  k3_chain<<<dim3(T_ / 64, B_), 256, 0, stream>>>(M, x, out);
}